// Round 3
// baseline (733.925 us; speedup 1.0000x reference)
//
#include <hip/hip_runtime.h>
#include <math.h>

#define BATCH 8
#define CCH 256
#define HW 40000
#define HW4 (HW / 4)          // 10000 float4 pixels per row
#define KSEL 8000
#define EPS_LN 1e-6f
#define EPS_COS 1e-8f

// ---- workspace layout (uint/float units) ----
// [0)        keys     : BATCH*HW uint (mono keys of score)
// [320000)   contrib  : BATCH*HW floats
// [640000)   hist1    : BATCH*65536 uint
// [1164288)  bsums    : 8 float
#define OFF_KEYS    0
#define OFF_CONTRIB 320000
#define OFF_HIST1   640000
#define OFF_BSUMS   1164288

typedef float v4f __attribute__((ext_vector_type(4)));
#define NT(p) __builtin_nontemporal_load(p)

__device__ __forceinline__ unsigned int mono_key(float x) {
  unsigned int u = __float_as_uint(x);
  return (u & 0x80000000u) ? ~u : (u | 0x80000000u);
}

// Zero hist1 (+ bsums). 524288 uints.
__global__ __launch_bounds__(256) void zero_kernel(unsigned int* __restrict__ ws) {
  const int n4 = (BATCH * 65536) / 4;  // uint4 count over hist1
  uint4* p = (uint4*)(ws + OFF_HIST1);
  uint4 z = {0u, 0u, 0u, 0u};
  for (int i = blockIdx.x * blockDim.x + threadIdx.x; i < n4; i += gridDim.x * blockDim.x)
    p[i] = z;
  if (blockIdx.x == 0 && threadIdx.x < BATCH) ws[OFF_BSUMS + threadIdx.x] = 0u;
}

// One thread per 4 consecutive pixels. Explicit software pipeline: two register
// banks of 8 channels each (16 float4 loads in flight), __launch_bounds__(256,1)
// so the allocator is allowed deep MLP instead of rolling the loop to 2
// outstanding loads (round-1 VGPR=36 -> 1.6 TB/s latency-bound).
// All arrays statically indexed (runtime-indexed ext_vector arrays -> scratch).
// Emits mono keys (ranking only needs order), contrib, and fused hist1.
__global__ __launch_bounds__(256, 1) void pixel_stats_kernel(
    const float* __restrict__ A, const float* __restrict__ B,
    unsigned int* __restrict__ keys, float* __restrict__ contrib,
    unsigned int* __restrict__ ws) {
  int tid = blockIdx.x * blockDim.x + threadIdx.x;
  if (tid >= BATCH * HW4) return;
  int b = tid / HW4;
  int p4 = tid - b * HW4;
  const v4f* a  = (const v4f*)(A + (size_t)b * CCH * HW) + p4;
  const v4f* bb = (const v4f*)(B + (size_t)b * CCH * HW) + p4;

  float sa[4] = {0, 0, 0, 0}, ssa[4] = {0, 0, 0, 0};
  float sb[4] = {0, 0, 0, 0}, ssb[4] = {0, 0, 0, 0}, dab[4] = {0, 0, 0, 0};

  v4f xA[8], yA[8], xB[8], yB[8];
  // prologue: channels 0..7 into bank A
#pragma unroll
  for (int k = 0; k < 8; ++k) {
    xA[k] = NT(a + (size_t)k * HW4);
    yA[k] = NT(bb + (size_t)k * HW4);
  }

#pragma unroll 1
  for (int it = 0; it < 16; ++it) {
    const size_t cb = (size_t)it * 16;
    // prefetch odd half (channels cb+8..cb+15) into bank B
#pragma unroll
    for (int k = 0; k < 8; ++k) {
      xB[k] = NT(a + (cb + 8 + (size_t)k) * HW4);
      yB[k] = NT(bb + (cb + 8 + (size_t)k) * HW4);
    }
    // accumulate bank A (channels cb..cb+7)
#pragma unroll
    for (int k = 0; k < 8; ++k) {
#pragma unroll
      for (int j = 0; j < 4; ++j) {
        float xs = xA[k][j], ys = yA[k][j];
        sa[j] += xs;  ssa[j] = fmaf(xs, xs, ssa[j]);
        sb[j] += ys;  ssb[j] = fmaf(ys, ys, ssb[j]);
        dab[j] = fmaf(xs, ys, dab[j]);
      }
    }
    // prefetch next even half into bank A
    if (it < 15) {
#pragma unroll
      for (int k = 0; k < 8; ++k) {
        xA[k] = NT(a + (cb + 16 + (size_t)k) * HW4);
        yA[k] = NT(bb + (cb + 16 + (size_t)k) * HW4);
      }
    }
    // accumulate bank B (channels cb+8..cb+15)
#pragma unroll
    for (int k = 0; k < 8; ++k) {
#pragma unroll
      for (int j = 0; j < 4; ++j) {
        float xs = xB[k][j], ys = yB[k][j];
        sa[j] += xs;  ssa[j] = fmaf(xs, xs, ssa[j]);
        sb[j] += ys;  ssb[j] = fmaf(ys, ys, ssb[j]);
        dab[j] = fmaf(xs, ys, dab[j]);
      }
    }
  }

  unsigned int kv[4];
  float cov[4];
  const float invC = 1.0f / (float)CCH;
#pragma unroll
  for (int j = 0; j < 4; ++j) {
    kv[j] = mono_key(ssa[j]);  // score = raw sum of squares
    float mua = sa[j] * invC, mub = sb[j] * invC;
    float cssa = fmaxf(ssa[j] - (float)CCH * mua * mua, 0.f);
    float cssb = fmaxf(ssb[j] - (float)CCH * mub * mub, 0.f);
    float cdot = dab[j] - (float)CCH * mua * mub;
    float siga = sqrtf(cssa / (float)(CCH - 1)) + EPS_LN;
    float sigb = sqrtf(cssb / (float)(CCH - 1)) + EPS_LN;
    float num = cdot / (siga * sigb);
    float na = sqrtf(cssa) / siga;
    float nb = sqrtf(cssb) / sigb;
    cov[j] = 1.0f - num / (fmaxf(na, EPS_COS) * fmaxf(nb, EPS_COS));
  }
  int out = b * HW + p4 * 4;
  *(uint4*)(keys + out)  = make_uint4(kv[0], kv[1], kv[2], kv[3]);
  *(v4f*)(contrib + out) = (v4f){cov[0], cov[1], cov[2], cov[3]};

  // fused hist1: top 16 bits of the monotone key
  unsigned int* h1 = ws + OFF_HIST1 + (b << 16);
#pragma unroll
  for (int j = 0; j < 4; ++j)
    atomicAdd(&h1[kv[j] >> 16], 1u);
}

// One block per batch (8 blocks x 1024). Radix-select: pass 0 over the global
// 65536-bin hist1 (top 16 bits), then two 8-bit refinement passes with 256-bin
// LDS histograms (re-reads the block's 160 KB key slice from L2/L3 — cheap,
// and avoids any global-atomic readback coherence question). Then sums the
// top-k contribs with an LDS tie counter. All selection state lives in LDS.
__global__ __launch_bounds__(1024) void select_sum_kernel(
    const unsigned int* __restrict__ keys, const float* __restrict__ contrib,
    unsigned int* __restrict__ ws) {
  int b = blockIdx.x;
  int t = threadIdx.x;
  const unsigned int* kb = keys + b * HW;
  const float* cbp = contrib + b * HW;

  __shared__ unsigned int suf[1024];
  __shared__ unsigned int bins[64];
  __shared__ unsigned int hbin[256];
  __shared__ unsigned int s_idx, s_above;
  __shared__ unsigned int s_tie;

  unsigned int prefix, K;

  // ---- pass 0: global hist1, K = KSEL -> prefix (top16), K = remaining ----
  {
    const unsigned int* h = ws + OFF_HIST1 + (b << 16);
    unsigned int sum = 0;
#pragma unroll 8
    for (int i = 0; i < 64; ++i) sum += h[t * 64 + i];
    suf[t] = sum;
    __syncthreads();
    // Hillis-Steele inclusive suffix scan: suf[t] = sum of chunks t..1023
    for (int off = 1; off < 1024; off <<= 1) {
      unsigned int v = (t + off < 1024) ? suf[t + off] : 0u;
      __syncthreads();
      suf[t] += v;
      __syncthreads();
    }
    unsigned int above = (t == 1023) ? 0u : suf[t + 1];
    if (suf[t] >= (unsigned)KSEL && above < (unsigned)KSEL) { s_idx = (unsigned)t; s_above = above; }
    __syncthreads();
    if (t < 64) bins[t] = h[s_idx * 64 + t];
    __syncthreads();
    if (t == 0) {
      unsigned int cum = s_above;
      int d = 63;
      for (; d >= 0; --d) {
        if (cum + bins[d] >= (unsigned)KSEL) break;
        cum += bins[d];
      }
      s_idx = s_idx * 64 + (unsigned)d;   // reuse s_idx for bin index
      s_above = cum;                      // count strictly above bin
    }
    __syncthreads();
    prefix = s_idx;
    K = (unsigned)KSEL - s_above;
    __syncthreads();
  }

  // ---- passes 1,2: 8-bit LDS refinement ----
  // pass 1: bins = bits[15:8] of keys with top16 == prefix
  // pass 2: bins = bits[7:0]  of keys with top24 == prefix
#pragma unroll 1
  for (int pass = 0; pass < 2; ++pass) {
    if (t < 256) hbin[t] = 0u;
    __syncthreads();
    if (pass == 0) {
      for (int i = t; i < HW; i += 1024) {
        unsigned int key = kb[i];
        if ((key >> 16) == prefix) atomicAdd(&hbin[(key >> 8) & 0xFFu], 1u);
      }
    } else {
      for (int i = t; i < HW; i += 1024) {
        unsigned int key = kb[i];
        if ((key >> 8) == prefix) atomicAdd(&hbin[key & 0xFFu], 1u);
      }
    }
    __syncthreads();
    // suffix scan over 256 bins
    if (t < 256) suf[t] = hbin[t];
    __syncthreads();
    for (int off = 1; off < 256; off <<= 1) {
      unsigned int v = (t < 256 && t + off < 256) ? suf[t + off] : 0u;
      __syncthreads();
      if (t < 256) suf[t] += v;
      __syncthreads();
    }
    if (t < 256) {
      unsigned int above = (t == 255) ? 0u : suf[t + 1];
      if (suf[t] >= K && above < K) { s_idx = (unsigned)t; s_above = above; }
    }
    __syncthreads();
    prefix = (prefix << 8) | s_idx;
    K = K - s_above;
    __syncthreads();
  }

  const unsigned int T = prefix;   // full 32-bit threshold key
  const unsigned int rem2 = K;     // ties to take at key == T
  if (t == 0) s_tie = 0u;
  __syncthreads();

  // ---- sum contribs: key > T always; key == T for first rem2 ----
  float partial = 0.f;
  for (int i = t; i < HW; i += 1024) {
    unsigned int key = kb[i];
    if (key > T) {
      partial += cbp[i];
    } else if (key == T) {
      unsigned int old = atomicAdd(&s_tie, 1u);
      if (old < rem2) partial += cbp[i];
    }
  }
  __syncthreads();
  float* redf = (float*)suf;
  redf[t] = partial;
  __syncthreads();
  for (int off = 512; off > 0; off >>= 1) {
    if (t < off) redf[t] += redf[t + off];
    __syncthreads();
  }
  if (t == 0) ((float*)(ws + OFF_BSUMS))[b] = redf[0];
}

__global__ void finalize_kernel(const unsigned int* __restrict__ ws,
                                const float* __restrict__ dx,
                                const float* __restrict__ dy,
                                const float* __restrict__ dth,
                                float* __restrict__ out) {
  if (threadIdx.x == 0 && blockIdx.x == 0) {
    const float* bsums = (const float*)(ws + OFF_BSUMS);
    float s = 0.f;
    for (int b = 0; b < BATCH; ++b) s += bsums[b];
    float align = s / (float)(BATCH * KSEL);
    float r1 = 0.f, r2 = 0.f;
    for (int b = 0; b < BATCH; ++b) {
      r1 += dx[b] * dx[b] + dy[b] * dy[b];
      r2 += dth[b] * dth[b];
    }
    out[0] = align + 0.1f * (r1 / (float)BATCH + r2 / (float)BATCH);
  }
}

extern "C" void kernel_launch(void* const* d_in, const int* in_sizes, int n_in,
                              void* d_out, int out_size, void* d_ws, size_t ws_size,
                              hipStream_t stream) {
  const float* bev   = (const float*)d_in[0];
  const float* prior = (const float*)d_in[1];
  const float* dx    = (const float*)d_in[2];
  const float* dy    = (const float*)d_in[3];
  const float* dth   = (const float*)d_in[4];
  float* out = (float*)d_out;

  unsigned int* ws = (unsigned int*)d_ws;
  unsigned int* keys = ws + OFF_KEYS;
  float* contrib     = (float*)ws + OFF_CONTRIB;

  zero_kernel<<<256, 256, 0, stream>>>(ws);
  pixel_stats_kernel<<<(BATCH * HW4 + 255) / 256, 256, 0, stream>>>(bev, prior, keys, contrib, ws);
  select_sum_kernel<<<BATCH, 1024, 0, stream>>>(keys, contrib, ws);
  finalize_kernel<<<1, 64, 0, stream>>>(ws, dx, dy, dth, out);
}